// Round 18
// baseline (1806.395 us; speedup 1.0000x reference)
//
#include <hip/hip_runtime.h>
#include <cstddef>

// ---------------------------------------------------------------------------
// RNNModel round 18: round-15/17 structure (best measured) + pre-work scrape:
//  (1) all 7 f32->hi|lo conversions merged into ONE conv_all launch,
//  (2) all init fills + bias perms merged into ONE init_all launch,
//  (3) dec_W conversion folded into rnn_dual as 64 poll-free converter blocks
//      (runs in the recurrence's shadow; stream order still guarantees
//      completion before the decoder dispatch).
// Recurrence + decoder kernels byte-identical to round 17 (1770us proven).
// ---------------------------------------------------------------------------

static constexpr int T_ = 50, B_ = 64, E_ = 1024, H_ = 1024, V_ = 32000;
static constexpr int G_ = 4096;

typedef unsigned short u16;
typedef unsigned int u32;
typedef unsigned long long u64;
typedef __attribute__((ext_vector_type(8))) short bf16x8;
typedef __attribute__((ext_vector_type(8))) unsigned short u16x8;
typedef __attribute__((ext_vector_type(4))) float f32x4;

__device__ __forceinline__ int perm_g(int n) {
  return ((n >> 4) & 3) * H_ + (n >> 6) * 16 + (n & 15);
}
__device__ __forceinline__ u16 bf16_rn(float x) {
  union { float f; unsigned u; } a; a.f = x;
  unsigned r = a.u + 0x7fffu + ((a.u >> 16) & 1u);
  return (u16)(r >> 16);
}
__device__ __forceinline__ float bf16_f(u16 h) {
  union { float f; unsigned u; } a; a.u = ((unsigned)h) << 16;
  return a.f;
}
__device__ __forceinline__ float sigm(float x) { return 1.f / (1.f + __expf(-x)); }

__global__ void fill_zero(float* p, int n) {
  int i = blockIdx.x * blockDim.x + threadIdx.x;
  if (i < n) p[i] = 0.f;
}
__global__ void bias_perm(const float* a, const float* b, float* dst) {
  int n = blockIdx.x * 256 + threadIdx.x;
  int s = perm_g(n);
  dst[n] = a[s] + b[s];
}

// shared conversion body: f32 row-slice -> interleaved hi|lo, chunk-XOR.
__device__ __forceinline__ void conv_body(
    const float* __restrict__ src, int srcld, int coloff,
    const int* __restrict__ gidx, int PERM, int rows,
    u16* __restrict__ dst, int idx) {
  int r = idx >> 7, kc = (idx & 127) << 3;
  if (r >= rows) return;
  int s = gidx ? gidx[r] : (PERM ? perm_g(r) : r);
  const float* p = src + (size_t)s * srcld + coloff + kc;
  float4 v0 = *(const float4*)p, v1 = *(const float4*)(p + 4);
  float vv[8] = {v0.x, v0.y, v0.z, v0.w, v1.x, v1.y, v1.z, v1.w};
  u16 hi[8], lo[8];
#pragma unroll
  for (int i = 0; i < 8; ++i) {
    hi[i] = bf16_rn(vv[i]);
    lo[i] = bf16_rn(vv[i] - bf16_f(hi[i]));
  }
  u16x8 c0, c1;
#pragma unroll
  for (int i = 0; i < 4; ++i) {
    c0[2 * i] = hi[i];     c0[2 * i + 1] = lo[i];
    c1[2 * i] = hi[4 + i]; c1[2 * i + 1] = lo[4 + i];
  }
  int seg = kc >> 5;
  int ch0 = (kc >> 2) & 7;
  size_t base = (size_t)r * 2048 + seg * 64;
  *(u16x8*)&dst[base + (size_t)((ch0 ^ (r & 7)) << 3)] = c0;
  *(u16x8*)&dst[base + (size_t)(((ch0 | 1) ^ (r & 7)) << 3)] = c1;
}

// legacy single-tensor conversion (tier2/3 decW etc.)
__global__ void conv_w(const float* __restrict__ src, int srcld, int coloff,
                       const int* __restrict__ gidx, int PERM, int rows,
                       u16* __restrict__ dst) {
  conv_body(src, srcld, coloff, gidx, PERM, rows, dst,
            blockIdx.x * 256 + threadIdx.x);
}

// ONE launch for all weight/embedding conversions (static job table).
__global__ void conv_all(const float* __restrict__ Wih0, const float* __restrict__ Wih1,
                         const float* __restrict__ Whh0, const float* __restrict__ Whh1,
                         const float* __restrict__ emb,
                         const int* __restrict__ word, const int* __restrict__ seq,
                         u16* wih0a, u16* wih0b, u16* wih1, u16* whh0, u16* whh1,
                         u16* x0w, u16* x0seq) {
  int b = blockIdx.x;
  if (b < 2048)
    conv_body(Wih0, 2048, 0, nullptr, 1, G_, wih0a, b * 256 + threadIdx.x);
  else if (b < 4096)
    conv_body(Wih0, 2048, 1024, nullptr, 1, G_, wih0b, (b - 2048) * 256 + threadIdx.x);
  else if (b < 6144)
    conv_body(Wih1, 1024, 0, nullptr, 1, G_, wih1, (b - 4096) * 256 + threadIdx.x);
  else if (b < 8192)
    conv_body(Whh0, 1024, 0, nullptr, 1, G_, whh0, (b - 6144) * 256 + threadIdx.x);
  else if (b < 10240)
    conv_body(Whh1, 1024, 0, nullptr, 1, G_, whh1, (b - 8192) * 256 + threadIdx.x);
  else if (b < 10272)
    conv_body(emb, 1024, 0, word, 0, B_, x0w, (b - 10240) * 256 + threadIdx.x);
  else
    conv_body(emb, 1024, 0, seq, 0, T_ * B_, x0seq, (b - 10272) * 256 + threadIdx.x);
}

// ONE launch: flag zeros, h-slot0 zeros (x2), both permuted biases.
__global__ void init_all(float* zf, float* z0, float* z1,
                         const float* bi0, const float* bh0, float* b0p,
                         const float* bi1, const float* bh1, float* b1p) {
  int b = blockIdx.x, tid = threadIdx.x;
  if (b < 32) {
    int i = b * 256 + tid;
    if (i < 8192) zf[i] = 0.f;
  } else if (b < 288) {
    z0[(b - 32) * 256 + tid] = 0.f;
  } else if (b < 544) {
    if (z1) z1[(b - 288) * 256 + tid] = 0.f;
  } else if (b < 560) {
    int n = (b - 544) * 256 + tid;
    int s = perm_g(n);
    b0p[n] = bi0[s] + bh0[s];
  } else {
    int n = (b - 560) * 256 + tid;
    int s = perm_g(n);
    b1p[n] = bi1[s] + bh1[s];
  }
}

// --------------- fp32 tiled GEMM (c0 init, dual store) ---------------------
template<int BM, int BN, int BK, int TM, int TN>
__launch_bounds__(256)
__global__ void gemm_nt(
    const float* __restrict__ A, const int* __restrict__ Aidx, int lda,
    const float* __restrict__ W, int ldw, int koff,
    const float* __restrict__ bias, float* __restrict__ C, float* __restrict__ C2,
    int ldc, int M, int N, int K) {
  constexpr int TX = BN / TN;
  constexpr int TY = BM / TM;
  static_assert(TX * TY == 256, "thread geometry");
  __shared__ float As[BK][BM + 4];
  __shared__ float Ws[BK][BN + 4];
  const int tid = threadIdx.x;
  const int tx = tid % TX, ty = tid / TX;
  const int m0 = blockIdx.y * BM, n0 = blockIdx.x * BN;
  float acc[TM][TN];
#pragma unroll
  for (int i = 0; i < TM; ++i)
#pragma unroll
    for (int j = 0; j < TN; ++j) acc[i][j] = 0.f;
  constexpr int AV = (BM * BK) / 4;
  constexpr int WV = (BN * BK) / 4;
  constexpr int KV = BK / 4;
  for (int k0 = 0; k0 < K; k0 += BK) {
#pragma unroll
    for (int lp = 0; lp < (AV + 255) / 256; ++lp) {
      int e = tid + lp * 256;
      if (e < AV) {
        int r = e / KV, kq = e % KV;
        int m = m0 + r;
        float4 v = make_float4(0.f, 0.f, 0.f, 0.f);
        if (m < M) {
          int row = Aidx ? Aidx[m] : m;
          v = *(const float4*)&A[(size_t)row * lda + k0 + kq * 4];
        }
        As[kq * 4 + 0][r] = v.x; As[kq * 4 + 1][r] = v.y;
        As[kq * 4 + 2][r] = v.z; As[kq * 4 + 3][r] = v.w;
      }
    }
#pragma unroll
    for (int lp = 0; lp < (WV + 255) / 256; ++lp) {
      int e = tid + lp * 256;
      if (e < WV) {
        int cc = e / KV, kq = e % KV;
        int n = n0 + cc;
        float4 v = make_float4(0.f, 0.f, 0.f, 0.f);
        if (n < N)
          v = *(const float4*)&W[(size_t)n * ldw + koff + k0 + kq * 4];
        Ws[kq * 4 + 0][cc] = v.x; Ws[kq * 4 + 1][cc] = v.y;
        Ws[kq * 4 + 2][cc] = v.z; Ws[kq * 4 + 3][cc] = v.w;
      }
    }
    __syncthreads();
#pragma unroll
    for (int kk = 0; kk < BK; ++kk) {
      float a[TM], b[TN];
#pragma unroll
      for (int i = 0; i < TM; ++i) a[i] = As[kk][ty * TM + i];
#pragma unroll
      for (int j = 0; j < TN; ++j) b[j] = Ws[kk][tx * TN + j];
#pragma unroll
      for (int i = 0; i < TM; ++i)
#pragma unroll
        for (int j = 0; j < TN; ++j)
          acc[i][j] += a[i] * b[j];
    }
    __syncthreads();
  }
#pragma unroll
  for (int i = 0; i < TM; ++i) {
    int m = m0 + ty * TM + i;
    if (m >= M) continue;
#pragma unroll
    for (int j = 0; j < TN; ++j) {
      int n = n0 + tx * TN + j;
      if (n >= N) continue;
      float v = acc[i][j];
      if (bias) v += bias[n];
      C[(size_t)m * ldc + n] = v;
      if (C2) C2[(size_t)m * ldc + n] = v;
    }
  }
}

// --------- pure-bf16 MFMA GEMM (round-11 single-buffered, proven) ----------
__launch_bounds__(256)
__global__ void gemm_bt(const u16* __restrict__ A, int Mrows,
                        const u16* __restrict__ Wb,
                        const float* __restrict__ bias,
                        const float* __restrict__ Dadd, int ldd, int dmask,
                        float* __restrict__ C, int ldc, int N, int nbx,
                        int mt, int ord) {
  __shared__ u16 lsA[128 * 64];
  __shared__ u16 lsB[128 * 64];

  int nwg = gridDim.x, bid = blockIdx.x;
  int q = nwg >> 3, r = nwg & 7;
  int xcd = bid & 7, base = bid >> 3;
  int wg = (xcd < r ? xcd * (q + 1) : r * (q + 1) + (xcd - r) * q) + base;
  int bx, by;
  if (ord) { by = wg % mt; bx = wg / mt; } else { bx = wg % nbx; by = wg / nbx; }
  const int m0 = by * 128, n0 = bx * 128;

  const int tid = threadIdx.x, w = tid >> 6, l = tid & 63;
  const int lr = l & 15, lq = l >> 4;
  const int wm = (w >> 1) * 64, wn = (w & 1) * 64;

  f32x4 acc[4][4] = {};

  for (int kt = 0; kt < 32; ++kt) {
#pragma unroll
    for (int i = 0; i < 4; ++i) {
      int rb = w * 32 + i * 8;
      int gm = m0 + rb + (l >> 3);
      if (gm > Mrows - 1) gm = Mrows - 1;
      const u16* ga = A + (size_t)gm * 2048 + kt * 64 + (l & 7) * 8;
      __builtin_amdgcn_global_load_lds(
          (const __attribute__((address_space(1))) void*)ga,
          (__attribute__((address_space(3))) void*)(lsA + rb * 64), 16, 0, 0);
      const u16* gb = Wb + (size_t)(n0 + rb + (l >> 3)) * 2048 + kt * 64 + (l & 7) * 8;
      __builtin_amdgcn_global_load_lds(
          (const __attribute__((address_space(1))) void*)gb,
          (__attribute__((address_space(3))) void*)(lsB + rb * 64), 16, 0, 0);
    }
    asm volatile("s_waitcnt vmcnt(0)" ::: "memory");
    __syncthreads();

    bf16x8 af[4][2], bfr[4][2];
#pragma unroll
    for (int i = 0; i < 4; ++i) {
      int ar = wm + i * 16 + lr;
#pragma unroll
      for (int s = 0; s < 2; ++s)
        af[i][s] = *(const bf16x8*)&lsA[ar * 64 + (((s << 2) + lq) ^ (ar & 7)) * 8];
    }
#pragma unroll
    for (int j = 0; j < 4; ++j) {
      int br = wn + j * 16 + lr;
#pragma unroll
      for (int s = 0; s < 2; ++s)
        bfr[j][s] = *(const bf16x8*)&lsB[br * 64 + (((s << 2) + lq) ^ (br & 7)) * 8];
    }
#pragma unroll
    for (int i = 0; i < 4; ++i)
#pragma unroll
      for (int j = 0; j < 4; ++j) {
        acc[i][j] = __builtin_amdgcn_mfma_f32_16x16x32_bf16(af[i][0], bfr[j][0], acc[i][j], 0, 0, 0);
        acc[i][j] = __builtin_amdgcn_mfma_f32_16x16x32_bf16(af[i][1], bfr[j][1], acc[i][j], 0, 0, 0);
      }
    __syncthreads();
  }

#pragma unroll
  for (int i = 0; i < 4; ++i) {
    int mbase = m0 + wm + i * 16 + lq * 4;
#pragma unroll
    for (int j = 0; j < 4; ++j) {
      int n = n0 + wn + j * 16 + lr;
      float badd = bias ? bias[n] : 0.f;
#pragma unroll
      for (int rr = 0; rr < 4; ++rr) {
        int m = mbase + rr;
        if (m >= Mrows) continue;
        float v = acc[i][j][rr] + badd;
        if (Dadd) {
          int dr = (dmask < 0) ? m : (m & dmask);
          v += Dadd[(size_t)dr * ldd + n];
        }
        C[(size_t)m * ldc + n] = v;
      }
    }
  }
}

// ----------- split-bf16 MFMA GEMM on f32 inputs (tier2/3 decoder) ----------
__launch_bounds__(256)
__global__ void gemm_sp(
    const float* __restrict__ A, int lda,
    const float* __restrict__ W, int ldw,
    const float* __restrict__ bias,
    float* __restrict__ C, int ldc, int M, int N, int K, int nbx) {
  __shared__ u16 As_h[128][40], As_l[128][40];
  __shared__ u16 Ws_h[128][40], Ws_l[128][40];
  int nwg = gridDim.x, bid = blockIdx.x;
  int q = nwg >> 3, r = nwg & 7;
  int xcd = bid & 7, base = bid >> 3;
  int wg = (xcd < r ? xcd * (q + 1) : r * (q + 1) + (xcd - r) * q) + base;
  int bx = wg % nbx, by = wg / nbx;
  const int m0 = by * 128, n0 = bx * 128;
  const int tid = threadIdx.x;
  const int wave = tid >> 6, lane = tid & 63;
  const int lr = lane & 15, lq = lane >> 4;
  const int wm = (wave >> 1) * 64, wn = (wave & 1) * 64;
  f32x4 acc[4][4] = {};
  for (int k0 = 0; k0 < K; k0 += 32) {
#pragma unroll
    for (int lp = 0; lp < 4; ++lp) {
      int s = tid + lp * 256;
      int row = s >> 3, kq = s & 7;
      float4 v = make_float4(0.f, 0.f, 0.f, 0.f);
      int gm = m0 + row;
      if (gm < M)
        v = *(const float4*)&A[(size_t)gm * lda + k0 + kq * 4];
      u16 h0 = bf16_rn(v.x), h1 = bf16_rn(v.y), h2 = bf16_rn(v.z), h3 = bf16_rn(v.w);
      u16 l0 = bf16_rn(v.x - bf16_f(h0)), l1 = bf16_rn(v.y - bf16_f(h1));
      u16 l2 = bf16_rn(v.z - bf16_f(h2)), l3 = bf16_rn(v.w - bf16_f(h3));
      *(uint2*)&As_h[row][kq * 4] =
          make_uint2((u32)h0 | ((u32)h1 << 16), (u32)h2 | ((u32)h3 << 16));
      *(uint2*)&As_l[row][kq * 4] =
          make_uint2((u32)l0 | ((u32)l1 << 16), (u32)l2 | ((u32)l3 << 16));
    }
#pragma unroll
    for (int lp = 0; lp < 4; ++lp) {
      int s = tid + lp * 256;
      int col = s >> 3, kq = s & 7;
      int n = n0 + col;
      float4 v = make_float4(0.f, 0.f, 0.f, 0.f);
      if (n < N)
        v = *(const float4*)&W[(size_t)n * ldw + k0 + kq * 4];
      u16 h0 = bf16_rn(v.x), h1 = bf16_rn(v.y), h2 = bf16_rn(v.z), h3 = bf16_rn(v.w);
      u16 l0 = bf16_rn(v.x - bf16_f(h0)), l1 = bf16_rn(v.y - bf16_f(h1));
      u16 l2 = bf16_rn(v.z - bf16_f(h2)), l3 = bf16_rn(v.w - bf16_f(h3));
      *(uint2*)&Ws_h[col][kq * 4] =
          make_uint2((u32)h0 | ((u32)h1 << 16), (u32)h2 | ((u32)h3 << 16));
      *(uint2*)&Ws_l[col][kq * 4] =
          make_uint2((u32)l0 | ((u32)l1 << 16), (u32)l2 | ((u32)l3 << 16));
    }
    __syncthreads();
    bf16x8 ah[4], al[4], bh[4], bl[4];
#pragma unroll
    for (int i = 0; i < 4; ++i) {
      ah[i] = *(const bf16x8*)&As_h[wm + i * 16 + lr][lq * 8];
      al[i] = *(const bf16x8*)&As_l[wm + i * 16 + lr][lq * 8];
    }
#pragma unroll
    for (int j = 0; j < 4; ++j) {
      bh[j] = *(const bf16x8*)&Ws_h[wn + j * 16 + lr][lq * 8];
      bl[j] = *(const bf16x8*)&Ws_l[wn + j * 16 + lr][lq * 8];
    }
#pragma unroll
    for (int i = 0; i < 4; ++i)
#pragma unroll
      for (int j = 0; j < 4; ++j) {
        acc[i][j] = __builtin_amdgcn_mfma_f32_16x16x32_bf16(ah[i], bh[j], acc[i][j], 0, 0, 0);
        acc[i][j] = __builtin_amdgcn_mfma_f32_16x16x32_bf16(ah[i], bl[j], acc[i][j], 0, 0, 0);
        acc[i][j] = __builtin_amdgcn_mfma_f32_16x16x32_bf16(al[i], bh[j], acc[i][j], 0, 0, 0);
      }
    __syncthreads();
  }
#pragma unroll
  for (int i = 0; i < 4; ++i) {
    int mbase = m0 + wm + i * 16 + lq * 4;
#pragma unroll
    for (int j = 0; j < 4; ++j) {
      int n = n0 + wn + j * 16 + lr;
      if (n >= N) continue;
      float badd = bias ? bias[n] : 0.f;
#pragma unroll
      for (int rr = 0; rr < 4; ++rr) {
        int m = mbase + rr;
        if (m >= M) continue;
        C[(size_t)m * ldc + n] = acc[i][j][rr] + badd;
      }
    }
  }
}

// ---------------- helpers for fused recurrence -----------------------------
__device__ __forceinline__ void gemm_half(
    const u32* __restrict__ hp, int rg, int w, int lr, int lq,
    const bf16x8 (&bfr)[8][4], f32x4 (&acc)[2][4]) {
  bf16x8 af[8][2];
#pragma unroll
  for (int s = 0; s < 8; ++s)
#pragma unroll
    for (int mt = 0; mt < 2; ++mt) {
      int m = rg * 32 + mt * 16 + lr;
      int seg = w * 4 + (s >> 1);
      int cis = ((((s & 1) << 2) + lq) ^ (lr & 7));
      const u32* p = hp + (size_t)m * 1024 + seg * 32 + cis * 4;
      asm volatile("global_load_dwordx4 %0, %1, off sc0 sc1"
                   : "=v"(af[s][mt]) : "v"(p) : "memory");
    }
  asm volatile("s_waitcnt vmcnt(0)" ::: "memory");
  __builtin_amdgcn_sched_barrier(0);
#pragma unroll
  for (int s = 0; s < 8; ++s)
#pragma unroll
    for (int mt = 0; mt < 2; ++mt)
#pragma unroll
      for (int nt = 0; nt < 4; ++nt)
        acc[mt][nt] = __builtin_amdgcn_mfma_f32_16x16x32_bf16(
            af[s][mt], bfr[s][nt], acc[mt][nt], 0, 0, 0);
}

// per-wave poll: wave w needs only writers ct in [8w, 8w+8) of its rg.
__device__ __forceinline__ void poll_src(const u32* flags, int rg, int w, int l, u32 tgt) {
  int guard = 0;
  for (;;) {
    u32 v = tgt;
    if (l < 8)
      v = __hip_atomic_load(flags + (size_t)((rg << 6) + (w << 3) + l) * 4,
                            __ATOMIC_RELAXED, __HIP_MEMORY_SCOPE_AGENT);
    if (__all(v >= tgt)) break;
    if (++guard > (1 << 23)) break;
    __builtin_amdgcn_s_sleep(1);
  }
}

// -------- fused dual-layer persistent recurrence (per-wave polling) --------
// CONVW: blocks >= 256 convert dec_W f32 -> hi|lo bf16 (poll-free, one pass)
// in the recurrence's shadow; they exit when done.
template<bool DUAL, bool EMIT, bool CONVW>
__launch_bounds__(512, 1)
__global__ void rnn_dual(const u16* __restrict__ Whh0b, const u16* __restrict__ Whh1b,
                         const u16* __restrict__ Wih1b,
                         const float* __restrict__ xg0all, const float* __restrict__ bias1p,
                         float* __restrict__ cL0, float* __restrict__ hL0,
                         float* __restrict__ cL1, float* __restrict__ hL1,
                         u32* __restrict__ h0s, u32* __restrict__ h1s,
                         float* __restrict__ hsf,
                         u32* __restrict__ flg0, u32* __restrict__ flg1,
                         const float* __restrict__ decW, u16* __restrict__ decWb,
                         int T) {
  __shared__ float partial[8][32][68];   // 69.6 KB

  const int bid = blockIdx.x;
  const int tid = threadIdx.x, w = tid >> 6, l = tid & 63;
  const int lr = l & 15, lq = l >> 4;

  if (CONVW && bid >= 256) {
    // converter block: rows [cb*500, cb*500+500) of dec_W (32000x1024 f32)
    const int cb = bid - 256;
    for (int it = 0; it < 125; ++it) {
      int e = it * 512 + tid;                  // 0..63999
      conv_body(decW, 1024, 0, nullptr, 0, V_, decWb, cb * 64000 + e);
    }
    return;
  }

  const int x = bid & 7, j = bid >> 3;
  const int layer = DUAL ? (j & 1) : 0;
  const int idx = DUAL ? (j >> 1) : j;
  const int ct = x * 8 + (idx & 7);
  const int rg = idx >> 3;

  // ---- recurrent-W fragments (cached loads; L2-resident per XCD)
  const u16* WbA = (layer ? Whh1b : Whh0b) + (size_t)(ct * 64) * 2048;
  bf16x8 bfragA[8][4];
#pragma unroll
  for (int s = 0; s < 8; ++s)
#pragma unroll
    for (int nt = 0; nt < 4; ++nt) {
      int row = nt * 16 + lr;
      int seg = w * 4 + (s >> 1);
      int cis = ((((s & 1) << 2) + lq) ^ (lr & 7));
      bfragA[s][nt] = *(const bf16x8*)&WbA[(size_t)row * 2048 + seg * 64 + cis * 8];
    }
  // ---- layer-1 only: Wih1 fragments
  bf16x8 bfragX[8][4];
  if (DUAL && layer) {
    const u16* WbX = Wih1b + (size_t)(ct * 64) * 2048;
#pragma unroll
    for (int s = 0; s < 8; ++s)
#pragma unroll
      for (int nt = 0; nt < 4; ++nt) {
        int row = nt * 16 + lr;
        int seg = w * 4 + (s >> 1);
        int cis = ((((s & 1) << 2) + lq) ^ (lr & 7));
        bfragX[s][nt] = *(const bf16x8*)&WbX[(size_t)row * 2048 + seg * 64 + cis * 8];
      }
  }

  // cell mapping
  const int cm = tid >> 4, cu = tid & 15;
  const int m_c = rg * 32 + cm;
  const int unit = ct * 16 + cu;
  float* cL = layer ? cL1 : cL0;
  float* hL = layer ? hL1 : hL0;
  u32* hsl = layer ? h1s : h0s;
  u32* flgS = layer ? flg1 : flg0;
  float creg = cL[m_c * H_ + unit];
  float bset[4];
  if (layer) {
#pragma unroll
    for (int g = 0; g < 4; ++g)
      bset[g] = bias1p[ct * 64 + g * 16 + cu];
  }

  for (int t = 0; t < T; ++t) {
    float xgv[4];
    if (!layer) {
      const float* xg = xg0all + (size_t)t * ((size_t)B_ * G_);
#pragma unroll
      for (int g = 0; g < 4; ++g)
        xgv[g] = xg[(size_t)m_c * G_ + ct * 64 + g * 16 + cu];
    } else {
#pragma unroll
      for (int g = 0; g < 4; ++g) xgv[g] = bset[g];
    }

    f32x4 acc[2][4] = {};

    if (layer) {
      // phase 1: own-layer h1[t] (per-wave wait; overlaps layer-0 step t)
      if (t) poll_src(flg1, rg, w, l, (u32)t);
      gemm_half(h1s + (size_t)t * (B_ * 1024), rg, w, lr, lq, bfragA, acc);
      // phase 2: hs0[t] from layer-0
      poll_src(flg0, rg, w, l, (u32)(t + 1));
      gemm_half(h0s + (size_t)(t + 1) * (B_ * 1024), rg, w, lr, lq, bfragX, acc);
    } else {
      if (t) poll_src(flg0, rg, w, l, (u32)t);
      gemm_half(h0s + (size_t)t * (B_ * 1024), rg, w, lr, lq, bfragA, acc);
    }

    // ---- K-split reduction through LDS (per-wave region; barrier gates reads)
#pragma unroll
    for (int mt = 0; mt < 2; ++mt)
#pragma unroll
      for (int nt = 0; nt < 4; ++nt)
#pragma unroll
        for (int rr = 0; rr < 4; ++rr)
          partial[w][mt * 16 + lq * 4 + rr][nt * 16 + lr] = acc[mt][nt][rr];
    __syncthreads();

    // ---- cell
    float g4[4];
#pragma unroll
    for (int g = 0; g < 4; ++g) {
      float ssum = xgv[g];
#pragma unroll
      for (int p = 0; p < 8; ++p) ssum += partial[p][cm][g * 16 + cu];
      g4[g] = ssum;
    }
    float cn = sigm(g4[1]) * creg + sigm(g4[0]) * tanhf(g4[2]);
    float hn = sigm(g4[3]) * tanhf(cn);
    creg = cn;
    if (EMIT && layer) hsf[(size_t)t * (B_ * H_) + m_c * H_ + unit] = hn;
    if (t == T - 1) { cL[m_c * H_ + unit] = cn; hL[m_c * H_ + unit] = hn; }
    u16 hh = bf16_rn(hn);
    u16 hl2 = bf16_rn(hn - bf16_f(hh));
    u32 packed = (u32)hh | ((u32)hl2 << 16);
    u32* hnext = hsl + (size_t)(t + 1) * (B_ * 1024);
    u32 hidx = m_c * 1024 + ((unit >> 5) << 5) +
               ((((unit >> 2) & 7) ^ (m_c & 7)) << 2) + (unit & 3);
    {
      u32* sp = hnext + hidx;
      asm volatile("global_store_dword %0, %1, off sc0 sc1"
                   :: "v"(sp), "v"(packed) : "memory");
    }

    // ---- publish (layer-0 always: layer-1 consumes even the last slot)
    if (!layer || t < T - 1) {
      asm volatile("s_waitcnt vmcnt(0)" ::: "memory");
      __syncthreads();
      if (tid == 0)
        __hip_atomic_store(flgS + (size_t)((rg << 6) + ct) * 4, (u32)(t + 1),
                           __ATOMIC_RELAXED, __HIP_MEMORY_SCOPE_AGENT);
    }
  }
}

// --------- single-step kernel (tiny-ws fallback), perm_g cell --------------
__launch_bounds__(256)
__global__ void rnn_step(const u16* __restrict__ hprev, const u16* __restrict__ Wb,
                         const float* __restrict__ xg,
                         float* __restrict__ c, float* __restrict__ hf,
                         u32* __restrict__ hout) {
  __shared__ char smem[32768];
  u16* lsA = (u16*)smem;
  u16* lsB = (u16*)(smem + 16384);
  const int nt = blockIdx.x, n0 = nt * 64;
  const int tid = threadIdx.x, w = tid >> 6, l = tid & 63;
  const int lr = l & 15, lq = l >> 4;
  f32x4 acc[4] = {};
  for (int kt = 0; kt < 16; ++kt) {
#pragma unroll
    for (int i = 0; i < 4; ++i) {
      int rb = w * 16 + i * 4;
      const u16* ga = hprev + (size_t)(rb + (l >> 4)) * 2048 + kt * 128 + (l & 15) * 8;
      __builtin_amdgcn_global_load_lds(
          (const __attribute__((address_space(1))) void*)ga,
          (__attribute__((address_space(3))) void*)(lsA + rb * 128), 16, 0, 0);
      const u16* gb = Wb + (size_t)(n0 + rb + (l >> 4)) * 2048 + kt * 128 + (l & 15) * 8;
      __builtin_amdgcn_global_load_lds(
          (const __attribute__((address_space(1))) void*)gb,
          (__attribute__((address_space(3))) void*)(lsB + rb * 128), 16, 0, 0);
    }
    asm volatile("s_waitcnt vmcnt(0)" ::: "memory");
    __syncthreads();
    bf16x8 af[4];
    int ar = w * 16 + lr;
#pragma unroll
    for (int s = 0; s < 4; ++s)
      af[s] = *(const bf16x8*)&lsA[ar * 128 + (s >> 1) * 64 + ((((s & 1) << 2) + lq) ^ (ar & 7)) * 8];
#pragma unroll
    for (int jj = 0; jj < 4; ++jj) {
      int br = jj * 16 + lr;
#pragma unroll
      for (int s = 0; s < 4; ++s) {
        bf16x8 bv = *(const bf16x8*)&lsB[br * 128 + (s >> 1) * 64 + ((((s & 1) << 2) + lq) ^ (br & 7)) * 8];
        acc[jj] = __builtin_amdgcn_mfma_f32_16x16x32_bf16(af[s], bv, acc[jj], 0, 0, 0);
      }
    }
    __syncthreads();
  }
  float* gsh = (float*)smem;
#pragma unroll
  for (int jj = 0; jj < 4; ++jj)
#pragma unroll
    for (int rr = 0; rr < 4; ++rr)
      gsh[(w * 16 + lq * 4 + rr) * 68 + jj * 16 + lr] = acc[jj][rr];
  __syncthreads();
  const int ui = tid & 15, mq = tid >> 4;
#pragma unroll
  for (int mr = 0; mr < 4; ++mr) {
    int m = mr * 16 + mq;
    float gi = gsh[m * 68 + 0 + ui]  + xg[(size_t)m * G_ + n0 + 0 + ui];
    float gf = gsh[m * 68 + 16 + ui] + xg[(size_t)m * G_ + n0 + 16 + ui];
    float gg = gsh[m * 68 + 32 + ui] + xg[(size_t)m * G_ + n0 + 32 + ui];
    float go = gsh[m * 68 + 48 + ui] + xg[(size_t)m * G_ + n0 + 48 + ui];
    int unit = nt * 16 + ui;
    int ci = m * H_ + unit;
    float cn = sigm(gf) * c[ci] + sigm(gi) * tanhf(gg);
    float hn = sigm(go) * tanhf(cn);
    c[ci] = cn;
    hf[ci] = hn;
    u16 hh = bf16_rn(hn);
    u16 hl = bf16_rn(hn - bf16_f(hh));
    u32 hidx = m * 1024 + ((unit >> 5) << 5) +
               ((((unit >> 2) & 7) ^ (m & 7)) << 2) + (unit & 3);
    hout[hidx] = (u32)hh | ((u32)hl << 16);
  }
}

// ---------------------------------------------------------------------------
extern "C" void kernel_launch(void* const* d_in, const int* in_sizes, int n_in,
                              void* d_out, int out_size, void* d_ws, size_t ws_size,
                              hipStream_t stream) {
  const int*   word  = (const int*)  d_in[0];
  const int*   seq   = (const int*)  d_in[1];
  const float* emb   = (const float*)d_in[2];
  const float* w2h_W = (const float*)d_in[3];
  const float* w2h_b = (const float*)d_in[4];
  const float* W_ih0 = (const float*)d_in[5];
  const float* W_hh0 = (const float*)d_in[6];
  const float* b_ih0 = (const float*)d_in[7];
  const float* b_hh0 = (const float*)d_in[8];
  const float* W_ih1 = (const float*)d_in[9];
  const float* W_hh1 = (const float*)d_in[10];
  const float* b_ih1 = (const float*)d_in[11];
  const float* b_hh1 = (const float*)d_in[12];
  const float* dec_W = (const float*)d_in[13];
  const float* dec_b = (const float*)d_in[14];

  float* out = (float*)d_out;
  float* hL0 = out + 102400000;
  float* hL1 = hL0 + B_ * H_;
  float* cL0 = out + 102531072;
  float* cL1 = cL0 + B_ * H_;

  // scratch in d_out (clobber-safe: decoder writes [0,102.4M) last)
  float* xg0      = out;                       // [3200,4096]
  u16*   x0w_bf   = (u16*)(out + 13200000);    // [64,2048]
  u16*   x0seq_bf = (u16*)(out + 13300000);    // [3200,2048]
  u32*   hs0slots = (u32*)(out + 16600000);    // [51][64][1024] u32-packed
  u16*   wih0a_bf = (u16*)(out + 20000000);    // [4096,2048] each
  u16*   wih0b_bf = (u16*)(out + 24200000);
  u16*   wih1_bf  = (u16*)(out + 28400000);
  u16*   whh0_bf  = (u16*)(out + 32600000);
  u16*   whh1_bf  = (u16*)(out + 36800000);
  float* y_w      = out + 73800000;            // [64,4096]
  float* bias0p   = out + 74400000;
  float* bias1p   = out + 74410000;
  float* xg1      = out + 87560192;            // tier3 only
  u32*   h1alt    = (u32*)(out + 91000000);    // tier2 h1 slots [51][64][1024]
  u32*   flg0     = (u32*)(out + 101000000);   // 128 flags x 4 u32 (16B stride)
  u32*   hbfA     = (u32*)(out + 101100000);   // tier3 ping-pong
  u32*   hbfB     = (u32*)(out + 101200000);

  const size_t need_hs1  = (size_t)T_ * B_ * H_ * 4;
  const size_t need_full = (size_t)V_ * 2048 * 2 + (size_t)(T_ + 1) * B_ * 1024 * 4;
  const bool tier1 = ws_size >= need_full;
  const bool tier2 = !tier1 && ws_size >= need_hs1;

  u16*   decW_bf  = (u16*)d_ws;
  u32*   hs1slots = (u32*)d_ws + (size_t)V_ * 1024;
  float* hs1f     = (float*)d_ws;

  // ONE init launch: flags (both sets, 8192 f), h0 slot0, h1 slot0, biases
  init_all<<<576, 256, 0, stream>>>(
      out + 101000000, (float*)hs0slots,
      tier1 ? (float*)hs1slots : (tier2 ? (float*)h1alt : nullptr),
      b_ih0, b_hh0, bias0p, b_ih1, b_hh1, bias1p);

  // c0 = word_emb @ w2h_W^T + w2h_b  (identical for both layers: dual store)
  gemm_nt<64, 64, 16, 4, 4><<<dim3(16, 1), 256, 0, stream>>>(
      emb, word, E_, w2h_W, E_, 0, w2h_b, cL0, cL1, H_, B_, H_, E_);

  // ONE conversion launch for all weights + gathered embeddings
  conv_all<<<11872, 256, 0, stream>>>(
      W_ih0, W_ih1, W_hh0, W_hh1, emb, word, seq,
      wih0a_bf, wih0b_bf, wih1_bf, whh0_bf, whh1_bf, x0w_bf, x0seq_bf);

  // y_w, xg0
  gemm_bt<<<32, 256, 0, stream>>>(x0w_bf, B_, wih0a_bf, bias0p,
                                  nullptr, 0, -1, y_w, G_, G_, 32, 1, 0);
  gemm_bt<<<800, 256, 0, stream>>>(x0seq_bf, T_ * B_, wih0b_bf, nullptr,
                                   y_w, G_, 63, xg0, G_, G_, 32, 25, 0);

  if (tier1) {
    // recurrence + 64 shadow converter blocks for dec_W
    rnn_dual<true, false, true><<<320, 512, 0, stream>>>(
        whh0_bf, whh1_bf, wih1_bf, xg0, bias1p,
        cL0, hL0, cL1, hL1, hs0slots, hs1slots, nullptr, flg0, flg0 + 1024,
        dec_W, decW_bf, T_);
    gemm_bt<<<6250, 256, 0, stream>>>((const u16*)(hs1slots + (size_t)B_ * 1024),
                                      T_ * B_, decW_bf, dec_b,
                                      nullptr, 0, -1, out, V_, V_, 250, 25, 1);
  } else if (tier2) {
    rnn_dual<true, true, false><<<256, 512, 0, stream>>>(
        whh0_bf, whh1_bf, wih1_bf, xg0, bias1p,
        cL0, hL0, cL1, hL1, hs0slots, h1alt, hs1f, flg0, flg0 + 1024,
        nullptr, nullptr, T_);
    gemm_sp<<<6250, 256, 0, stream>>>(
        hs1f, H_, dec_W, H_, dec_b, out, V_, T_ * B_, V_, H_, 250);
  } else {
    // tier3: layer-0 solo persistent, then sequential layer-1 + decode
    rnn_dual<false, false, false><<<128, 512, 0, stream>>>(
        whh0_bf, whh1_bf, wih1_bf, xg0, bias1p,
        cL0, hL0, cL1, hL1, hs0slots, nullptr, nullptr, flg0, flg0 + 1024,
        nullptr, nullptr, T_);
    gemm_bt<<<800, 256, 0, stream>>>((const u16*)(hs0slots + (size_t)B_ * 1024),
                                     T_ * B_, wih1_bf, bias1p,
                                     nullptr, 0, -1, xg1, G_, G_, 32, 25, 0);
    for (int t = 0; t < T_; ++t) {
      const u16* hp = t ? (const u16*)((t & 1) ? hbfA : hbfB) : (const u16*)hs0slots;
      u32* ho = (t & 1) ? hbfB : hbfA;
      rnn_step<<<64, 256, 0, stream>>>(
          hp, whh1_bf, xg1 + (size_t)t * B_ * G_, cL1, hL1, ho);
      gemm_sp<<<250, 256, 0, stream>>>(
          hL1, H_, dec_W, H_, dec_b, out + (size_t)t * B_ * V_, V_, B_, V_, H_, 250);
    }
  }
}

// Round 19
// 1744.096 us; speedup vs baseline: 1.0357x; 1.0357x over previous
//
#include <hip/hip_runtime.h>
#include <cstddef>

// ---------------------------------------------------------------------------
// RNNModel round 19: round-17 structure + KEPT launch merges (conv_all,
// init_all: −~50us prework) + REVERTED shadow dec_W converter (r18 showed it
// costs the recurrence +132us vs saving 45us). dec_W conversion back as a
// serial conv_w launch. Recurrence/decoder byte-identical to round 17.
// ---------------------------------------------------------------------------

static constexpr int T_ = 50, B_ = 64, E_ = 1024, H_ = 1024, V_ = 32000;
static constexpr int G_ = 4096;

typedef unsigned short u16;
typedef unsigned int u32;
typedef unsigned long long u64;
typedef __attribute__((ext_vector_type(8))) short bf16x8;
typedef __attribute__((ext_vector_type(8))) unsigned short u16x8;
typedef __attribute__((ext_vector_type(4))) float f32x4;

__device__ __forceinline__ int perm_g(int n) {
  return ((n >> 4) & 3) * H_ + (n >> 6) * 16 + (n & 15);
}
__device__ __forceinline__ u16 bf16_rn(float x) {
  union { float f; unsigned u; } a; a.f = x;
  unsigned r = a.u + 0x7fffu + ((a.u >> 16) & 1u);
  return (u16)(r >> 16);
}
__device__ __forceinline__ float bf16_f(u16 h) {
  union { float f; unsigned u; } a; a.u = ((unsigned)h) << 16;
  return a.f;
}
__device__ __forceinline__ float sigm(float x) { return 1.f / (1.f + __expf(-x)); }

// shared conversion body: f32 row-slice -> interleaved hi|lo, chunk-XOR.
__device__ __forceinline__ void conv_body(
    const float* __restrict__ src, int srcld, int coloff,
    const int* __restrict__ gidx, int PERM, int rows,
    u16* __restrict__ dst, int idx) {
  int r = idx >> 7, kc = (idx & 127) << 3;
  if (r >= rows) return;
  int s = gidx ? gidx[r] : (PERM ? perm_g(r) : r);
  const float* p = src + (size_t)s * srcld + coloff + kc;
  float4 v0 = *(const float4*)p, v1 = *(const float4*)(p + 4);
  float vv[8] = {v0.x, v0.y, v0.z, v0.w, v1.x, v1.y, v1.z, v1.w};
  u16 hi[8], lo[8];
#pragma unroll
  for (int i = 0; i < 8; ++i) {
    hi[i] = bf16_rn(vv[i]);
    lo[i] = bf16_rn(vv[i] - bf16_f(hi[i]));
  }
  u16x8 c0, c1;
#pragma unroll
  for (int i = 0; i < 4; ++i) {
    c0[2 * i] = hi[i];     c0[2 * i + 1] = lo[i];
    c1[2 * i] = hi[4 + i]; c1[2 * i + 1] = lo[4 + i];
  }
  int seg = kc >> 5;
  int ch0 = (kc >> 2) & 7;
  size_t base = (size_t)r * 2048 + seg * 64;
  *(u16x8*)&dst[base + (size_t)((ch0 ^ (r & 7)) << 3)] = c0;
  *(u16x8*)&dst[base + (size_t)(((ch0 | 1) ^ (r & 7)) << 3)] = c1;
}

// single-tensor conversion (dec_W, tier2/3 paths)
__global__ void conv_w(const float* __restrict__ src, int srcld, int coloff,
                       const int* __restrict__ gidx, int PERM, int rows,
                       u16* __restrict__ dst) {
  conv_body(src, srcld, coloff, gidx, PERM, rows, dst,
            blockIdx.x * 256 + threadIdx.x);
}

// ONE launch for all weight/embedding conversions (static job table).
__global__ void conv_all(const float* __restrict__ Wih0, const float* __restrict__ Wih1,
                         const float* __restrict__ Whh0, const float* __restrict__ Whh1,
                         const float* __restrict__ emb,
                         const int* __restrict__ word, const int* __restrict__ seq,
                         u16* wih0a, u16* wih0b, u16* wih1, u16* whh0, u16* whh1,
                         u16* x0w, u16* x0seq) {
  int b = blockIdx.x;
  if (b < 2048)
    conv_body(Wih0, 2048, 0, nullptr, 1, G_, wih0a, b * 256 + threadIdx.x);
  else if (b < 4096)
    conv_body(Wih0, 2048, 1024, nullptr, 1, G_, wih0b, (b - 2048) * 256 + threadIdx.x);
  else if (b < 6144)
    conv_body(Wih1, 1024, 0, nullptr, 1, G_, wih1, (b - 4096) * 256 + threadIdx.x);
  else if (b < 8192)
    conv_body(Whh0, 1024, 0, nullptr, 1, G_, whh0, (b - 6144) * 256 + threadIdx.x);
  else if (b < 10240)
    conv_body(Whh1, 1024, 0, nullptr, 1, G_, whh1, (b - 8192) * 256 + threadIdx.x);
  else if (b < 10272)
    conv_body(emb, 1024, 0, word, 0, B_, x0w, (b - 10240) * 256 + threadIdx.x);
  else
    conv_body(emb, 1024, 0, seq, 0, T_ * B_, x0seq, (b - 10272) * 256 + threadIdx.x);
}

// ONE launch: flag zeros, h-slot0 zeros (x2), both permuted biases.
__global__ void init_all(float* zf, float* z0, float* z1,
                         const float* bi0, const float* bh0, float* b0p,
                         const float* bi1, const float* bh1, float* b1p) {
  int b = blockIdx.x, tid = threadIdx.x;
  if (b < 32) {
    int i = b * 256 + tid;
    if (i < 8192) zf[i] = 0.f;
  } else if (b < 288) {
    z0[(b - 32) * 256 + tid] = 0.f;
  } else if (b < 544) {
    if (z1) z1[(b - 288) * 256 + tid] = 0.f;
  } else if (b < 560) {
    int n = (b - 544) * 256 + tid;
    int s = perm_g(n);
    b0p[n] = bi0[s] + bh0[s];
  } else {
    int n = (b - 560) * 256 + tid;
    int s = perm_g(n);
    b1p[n] = bi1[s] + bh1[s];
  }
}

// --------------- fp32 tiled GEMM (c0 init, dual store) ---------------------
template<int BM, int BN, int BK, int TM, int TN>
__launch_bounds__(256)
__global__ void gemm_nt(
    const float* __restrict__ A, const int* __restrict__ Aidx, int lda,
    const float* __restrict__ W, int ldw, int koff,
    const float* __restrict__ bias, float* __restrict__ C, float* __restrict__ C2,
    int ldc, int M, int N, int K) {
  constexpr int TX = BN / TN;
  constexpr int TY = BM / TM;
  static_assert(TX * TY == 256, "thread geometry");
  __shared__ float As[BK][BM + 4];
  __shared__ float Ws[BK][BN + 4];
  const int tid = threadIdx.x;
  const int tx = tid % TX, ty = tid / TX;
  const int m0 = blockIdx.y * BM, n0 = blockIdx.x * BN;
  float acc[TM][TN];
#pragma unroll
  for (int i = 0; i < TM; ++i)
#pragma unroll
    for (int j = 0; j < TN; ++j) acc[i][j] = 0.f;
  constexpr int AV = (BM * BK) / 4;
  constexpr int WV = (BN * BK) / 4;
  constexpr int KV = BK / 4;
  for (int k0 = 0; k0 < K; k0 += BK) {
#pragma unroll
    for (int lp = 0; lp < (AV + 255) / 256; ++lp) {
      int e = tid + lp * 256;
      if (e < AV) {
        int r = e / KV, kq = e % KV;
        int m = m0 + r;
        float4 v = make_float4(0.f, 0.f, 0.f, 0.f);
        if (m < M) {
          int row = Aidx ? Aidx[m] : m;
          v = *(const float4*)&A[(size_t)row * lda + k0 + kq * 4];
        }
        As[kq * 4 + 0][r] = v.x; As[kq * 4 + 1][r] = v.y;
        As[kq * 4 + 2][r] = v.z; As[kq * 4 + 3][r] = v.w;
      }
    }
#pragma unroll
    for (int lp = 0; lp < (WV + 255) / 256; ++lp) {
      int e = tid + lp * 256;
      if (e < WV) {
        int cc = e / KV, kq = e % KV;
        int n = n0 + cc;
        float4 v = make_float4(0.f, 0.f, 0.f, 0.f);
        if (n < N)
          v = *(const float4*)&W[(size_t)n * ldw + koff + k0 + kq * 4];
        Ws[kq * 4 + 0][cc] = v.x; Ws[kq * 4 + 1][cc] = v.y;
        Ws[kq * 4 + 2][cc] = v.z; Ws[kq * 4 + 3][cc] = v.w;
      }
    }
    __syncthreads();
#pragma unroll
    for (int kk = 0; kk < BK; ++kk) {
      float a[TM], b[TN];
#pragma unroll
      for (int i = 0; i < TM; ++i) a[i] = As[kk][ty * TM + i];
#pragma unroll
      for (int j = 0; j < TN; ++j) b[j] = Ws[kk][tx * TN + j];
#pragma unroll
      for (int i = 0; i < TM; ++i)
#pragma unroll
        for (int j = 0; j < TN; ++j)
          acc[i][j] += a[i] * b[j];
    }
    __syncthreads();
  }
#pragma unroll
  for (int i = 0; i < TM; ++i) {
    int m = m0 + ty * TM + i;
    if (m >= M) continue;
#pragma unroll
    for (int j = 0; j < TN; ++j) {
      int n = n0 + tx * TN + j;
      if (n >= N) continue;
      float v = acc[i][j];
      if (bias) v += bias[n];
      C[(size_t)m * ldc + n] = v;
      if (C2) C2[(size_t)m * ldc + n] = v;
    }
  }
}

// --------- pure-bf16 MFMA GEMM (round-11 single-buffered, proven) ----------
__launch_bounds__(256)
__global__ void gemm_bt(const u16* __restrict__ A, int Mrows,
                        const u16* __restrict__ Wb,
                        const float* __restrict__ bias,
                        const float* __restrict__ Dadd, int ldd, int dmask,
                        float* __restrict__ C, int ldc, int N, int nbx,
                        int mt, int ord) {
  __shared__ u16 lsA[128 * 64];
  __shared__ u16 lsB[128 * 64];

  int nwg = gridDim.x, bid = blockIdx.x;
  int q = nwg >> 3, r = nwg & 7;
  int xcd = bid & 7, base = bid >> 3;
  int wg = (xcd < r ? xcd * (q + 1) : r * (q + 1) + (xcd - r) * q) + base;
  int bx, by;
  if (ord) { by = wg % mt; bx = wg / mt; } else { bx = wg % nbx; by = wg / nbx; }
  const int m0 = by * 128, n0 = bx * 128;

  const int tid = threadIdx.x, w = tid >> 6, l = tid & 63;
  const int lr = l & 15, lq = l >> 4;
  const int wm = (w >> 1) * 64, wn = (w & 1) * 64;

  f32x4 acc[4][4] = {};

  for (int kt = 0; kt < 32; ++kt) {
#pragma unroll
    for (int i = 0; i < 4; ++i) {
      int rb = w * 32 + i * 8;
      int gm = m0 + rb + (l >> 3);
      if (gm > Mrows - 1) gm = Mrows - 1;
      const u16* ga = A + (size_t)gm * 2048 + kt * 64 + (l & 7) * 8;
      __builtin_amdgcn_global_load_lds(
          (const __attribute__((address_space(1))) void*)ga,
          (__attribute__((address_space(3))) void*)(lsA + rb * 64), 16, 0, 0);
      const u16* gb = Wb + (size_t)(n0 + rb + (l >> 3)) * 2048 + kt * 64 + (l & 7) * 8;
      __builtin_amdgcn_global_load_lds(
          (const __attribute__((address_space(1))) void*)gb,
          (__attribute__((address_space(3))) void*)(lsB + rb * 64), 16, 0, 0);
    }
    asm volatile("s_waitcnt vmcnt(0)" ::: "memory");
    __syncthreads();

    bf16x8 af[4][2], bfr[4][2];
#pragma unroll
    for (int i = 0; i < 4; ++i) {
      int ar = wm + i * 16 + lr;
#pragma unroll
      for (int s = 0; s < 2; ++s)
        af[i][s] = *(const bf16x8*)&lsA[ar * 64 + (((s << 2) + lq) ^ (ar & 7)) * 8];
    }
#pragma unroll
    for (int j = 0; j < 4; ++j) {
      int br = wn + j * 16 + lr;
#pragma unroll
      for (int s = 0; s < 2; ++s)
        bfr[j][s] = *(const bf16x8*)&lsB[br * 64 + (((s << 2) + lq) ^ (br & 7)) * 8];
    }
#pragma unroll
    for (int i = 0; i < 4; ++i)
#pragma unroll
      for (int j = 0; j < 4; ++j) {
        acc[i][j] = __builtin_amdgcn_mfma_f32_16x16x32_bf16(af[i][0], bfr[j][0], acc[i][j], 0, 0, 0);
        acc[i][j] = __builtin_amdgcn_mfma_f32_16x16x32_bf16(af[i][1], bfr[j][1], acc[i][j], 0, 0, 0);
      }
    __syncthreads();
  }

#pragma unroll
  for (int i = 0; i < 4; ++i) {
    int mbase = m0 + wm + i * 16 + lq * 4;
#pragma unroll
    for (int j = 0; j < 4; ++j) {
      int n = n0 + wn + j * 16 + lr;
      float badd = bias ? bias[n] : 0.f;
#pragma unroll
      for (int rr = 0; rr < 4; ++rr) {
        int m = mbase + rr;
        if (m >= Mrows) continue;
        float v = acc[i][j][rr] + badd;
        if (Dadd) {
          int dr = (dmask < 0) ? m : (m & dmask);
          v += Dadd[(size_t)dr * ldd + n];
        }
        C[(size_t)m * ldc + n] = v;
      }
    }
  }
}

// ----------- split-bf16 MFMA GEMM on f32 inputs (tier2/3 decoder) ----------
__launch_bounds__(256)
__global__ void gemm_sp(
    const float* __restrict__ A, int lda,
    const float* __restrict__ W, int ldw,
    const float* __restrict__ bias,
    float* __restrict__ C, int ldc, int M, int N, int K, int nbx) {
  __shared__ u16 As_h[128][40], As_l[128][40];
  __shared__ u16 Ws_h[128][40], Ws_l[128][40];
  int nwg = gridDim.x, bid = blockIdx.x;
  int q = nwg >> 3, r = nwg & 7;
  int xcd = bid & 7, base = bid >> 3;
  int wg = (xcd < r ? xcd * (q + 1) : r * (q + 1) + (xcd - r) * q) + base;
  int bx = wg % nbx, by = wg / nbx;
  const int m0 = by * 128, n0 = bx * 128;
  const int tid = threadIdx.x;
  const int wave = tid >> 6, lane = tid & 63;
  const int lr = lane & 15, lq = lane >> 4;
  const int wm = (wave >> 1) * 64, wn = (wave & 1) * 64;
  f32x4 acc[4][4] = {};
  for (int k0 = 0; k0 < K; k0 += 32) {
#pragma unroll
    for (int lp = 0; lp < 4; ++lp) {
      int s = tid + lp * 256;
      int row = s >> 3, kq = s & 7;
      float4 v = make_float4(0.f, 0.f, 0.f, 0.f);
      int gm = m0 + row;
      if (gm < M)
        v = *(const float4*)&A[(size_t)gm * lda + k0 + kq * 4];
      u16 h0 = bf16_rn(v.x), h1 = bf16_rn(v.y), h2 = bf16_rn(v.z), h3 = bf16_rn(v.w);
      u16 l0 = bf16_rn(v.x - bf16_f(h0)), l1 = bf16_rn(v.y - bf16_f(h1));
      u16 l2 = bf16_rn(v.z - bf16_f(h2)), l3 = bf16_rn(v.w - bf16_f(h3));
      *(uint2*)&As_h[row][kq * 4] =
          make_uint2((u32)h0 | ((u32)h1 << 16), (u32)h2 | ((u32)h3 << 16));
      *(uint2*)&As_l[row][kq * 4] =
          make_uint2((u32)l0 | ((u32)l1 << 16), (u32)l2 | ((u32)l3 << 16));
    }
#pragma unroll
    for (int lp = 0; lp < 4; ++lp) {
      int s = tid + lp * 256;
      int col = s >> 3, kq = s & 7;
      int n = n0 + col;
      float4 v = make_float4(0.f, 0.f, 0.f, 0.f);
      if (n < N)
        v = *(const float4*)&W[(size_t)n * ldw + k0 + kq * 4];
      u16 h0 = bf16_rn(v.x), h1 = bf16_rn(v.y), h2 = bf16_rn(v.z), h3 = bf16_rn(v.w);
      u16 l0 = bf16_rn(v.x - bf16_f(h0)), l1 = bf16_rn(v.y - bf16_f(h1));
      u16 l2 = bf16_rn(v.z - bf16_f(h2)), l3 = bf16_rn(v.w - bf16_f(h3));
      *(uint2*)&Ws_h[col][kq * 4] =
          make_uint2((u32)h0 | ((u32)h1 << 16), (u32)h2 | ((u32)h3 << 16));
      *(uint2*)&Ws_l[col][kq * 4] =
          make_uint2((u32)l0 | ((u32)l1 << 16), (u32)l2 | ((u32)l3 << 16));
    }
    __syncthreads();
    bf16x8 ah[4], al[4], bh[4], bl[4];
#pragma unroll
    for (int i = 0; i < 4; ++i) {
      ah[i] = *(const bf16x8*)&As_h[wm + i * 16 + lr][lq * 8];
      al[i] = *(const bf16x8*)&As_l[wm + i * 16 + lr][lq * 8];
    }
#pragma unroll
    for (int j = 0; j < 4; ++j) {
      bh[j] = *(const bf16x8*)&Ws_h[wn + j * 16 + lr][lq * 8];
      bl[j] = *(const bf16x8*)&Ws_l[wn + j * 16 + lr][lq * 8];
    }
#pragma unroll
    for (int i = 0; i < 4; ++i)
#pragma unroll
      for (int j = 0; j < 4; ++j) {
        acc[i][j] = __builtin_amdgcn_mfma_f32_16x16x32_bf16(ah[i], bh[j], acc[i][j], 0, 0, 0);
        acc[i][j] = __builtin_amdgcn_mfma_f32_16x16x32_bf16(ah[i], bl[j], acc[i][j], 0, 0, 0);
        acc[i][j] = __builtin_amdgcn_mfma_f32_16x16x32_bf16(al[i], bh[j], acc[i][j], 0, 0, 0);
      }
    __syncthreads();
  }
#pragma unroll
  for (int i = 0; i < 4; ++i) {
    int mbase = m0 + wm + i * 16 + lq * 4;
#pragma unroll
    for (int j = 0; j < 4; ++j) {
      int n = n0 + wn + j * 16 + lr;
      if (n >= N) continue;
      float badd = bias ? bias[n] : 0.f;
#pragma unroll
      for (int rr = 0; rr < 4; ++rr) {
        int m = mbase + rr;
        if (m >= M) continue;
        C[(size_t)m * ldc + n] = acc[i][j][rr] + badd;
      }
    }
  }
}

// ---------------- helpers for fused recurrence -----------------------------
__device__ __forceinline__ void gemm_half(
    const u32* __restrict__ hp, int rg, int w, int lr, int lq,
    const bf16x8 (&bfr)[8][4], f32x4 (&acc)[2][4]) {
  bf16x8 af[8][2];
#pragma unroll
  for (int s = 0; s < 8; ++s)
#pragma unroll
    for (int mt = 0; mt < 2; ++mt) {
      int m = rg * 32 + mt * 16 + lr;
      int seg = w * 4 + (s >> 1);
      int cis = ((((s & 1) << 2) + lq) ^ (lr & 7));
      const u32* p = hp + (size_t)m * 1024 + seg * 32 + cis * 4;
      asm volatile("global_load_dwordx4 %0, %1, off sc0 sc1"
                   : "=v"(af[s][mt]) : "v"(p) : "memory");
    }
  asm volatile("s_waitcnt vmcnt(0)" ::: "memory");
  __builtin_amdgcn_sched_barrier(0);
#pragma unroll
  for (int s = 0; s < 8; ++s)
#pragma unroll
    for (int mt = 0; mt < 2; ++mt)
#pragma unroll
      for (int nt = 0; nt < 4; ++nt)
        acc[mt][nt] = __builtin_amdgcn_mfma_f32_16x16x32_bf16(
            af[s][mt], bfr[s][nt], acc[mt][nt], 0, 0, 0);
}

// per-wave poll: wave w needs only writers ct in [8w, 8w+8) of its rg.
__device__ __forceinline__ void poll_src(const u32* flags, int rg, int w, int l, u32 tgt) {
  int guard = 0;
  for (;;) {
    u32 v = tgt;
    if (l < 8)
      v = __hip_atomic_load(flags + (size_t)((rg << 6) + (w << 3) + l) * 4,
                            __ATOMIC_RELAXED, __HIP_MEMORY_SCOPE_AGENT);
    if (__all(v >= tgt)) break;
    if (++guard > (1 << 23)) break;
    __builtin_amdgcn_s_sleep(1);
  }
}

// -------- fused dual-layer persistent recurrence (per-wave polling) --------
template<bool DUAL, bool EMIT>
__launch_bounds__(512, 1)
__global__ void rnn_dual(const u16* __restrict__ Whh0b, const u16* __restrict__ Whh1b,
                         const u16* __restrict__ Wih1b,
                         const float* __restrict__ xg0all, const float* __restrict__ bias1p,
                         float* __restrict__ cL0, float* __restrict__ hL0,
                         float* __restrict__ cL1, float* __restrict__ hL1,
                         u32* __restrict__ h0s, u32* __restrict__ h1s,
                         float* __restrict__ hsf,
                         u32* __restrict__ flg0, u32* __restrict__ flg1, int T) {
  __shared__ float partial[8][32][68];   // 69.6 KB

  const int bid = blockIdx.x;
  const int x = bid & 7, j = bid >> 3;
  const int layer = DUAL ? (j & 1) : 0;
  const int idx = DUAL ? (j >> 1) : j;
  const int ct = x * 8 + (idx & 7);
  const int rg = idx >> 3;
  const int tid = threadIdx.x, w = tid >> 6, l = tid & 63;
  const int lr = l & 15, lq = l >> 4;

  // ---- recurrent-W fragments (cached loads; L2-resident per XCD)
  const u16* WbA = (layer ? Whh1b : Whh0b) + (size_t)(ct * 64) * 2048;
  bf16x8 bfragA[8][4];
#pragma unroll
  for (int s = 0; s < 8; ++s)
#pragma unroll
    for (int nt = 0; nt < 4; ++nt) {
      int row = nt * 16 + lr;
      int seg = w * 4 + (s >> 1);
      int cis = ((((s & 1) << 2) + lq) ^ (lr & 7));
      bfragA[s][nt] = *(const bf16x8*)&WbA[(size_t)row * 2048 + seg * 64 + cis * 8];
    }
  // ---- layer-1 only: Wih1 fragments
  bf16x8 bfragX[8][4];
  if (DUAL && layer) {
    const u16* WbX = Wih1b + (size_t)(ct * 64) * 2048;
#pragma unroll
    for (int s = 0; s < 8; ++s)
#pragma unroll
      for (int nt = 0; nt < 4; ++nt) {
        int row = nt * 16 + lr;
        int seg = w * 4 + (s >> 1);
        int cis = ((((s & 1) << 2) + lq) ^ (lr & 7));
        bfragX[s][nt] = *(const bf16x8*)&WbX[(size_t)row * 2048 + seg * 64 + cis * 8];
      }
  }

  // cell mapping
  const int cm = tid >> 4, cu = tid & 15;
  const int m_c = rg * 32 + cm;
  const int unit = ct * 16 + cu;
  float* cL = layer ? cL1 : cL0;
  float* hL = layer ? hL1 : hL0;
  u32* hsl = layer ? h1s : h0s;
  u32* flgS = layer ? flg1 : flg0;
  float creg = cL[m_c * H_ + unit];
  float bset[4];
  if (layer) {
#pragma unroll
    for (int g = 0; g < 4; ++g)
      bset[g] = bias1p[ct * 64 + g * 16 + cu];
  }

  for (int t = 0; t < T; ++t) {
    float xgv[4];
    if (!layer) {
      const float* xg = xg0all + (size_t)t * ((size_t)B_ * G_);
#pragma unroll
      for (int g = 0; g < 4; ++g)
        xgv[g] = xg[(size_t)m_c * G_ + ct * 64 + g * 16 + cu];
    } else {
#pragma unroll
      for (int g = 0; g < 4; ++g) xgv[g] = bset[g];
    }

    f32x4 acc[2][4] = {};

    if (layer) {
      // phase 1: own-layer h1[t] (per-wave wait; overlaps layer-0 step t)
      if (t) poll_src(flg1, rg, w, l, (u32)t);
      gemm_half(h1s + (size_t)t * (B_ * 1024), rg, w, lr, lq, bfragA, acc);
      // phase 2: hs0[t] from layer-0
      poll_src(flg0, rg, w, l, (u32)(t + 1));
      gemm_half(h0s + (size_t)(t + 1) * (B_ * 1024), rg, w, lr, lq, bfragX, acc);
    } else {
      if (t) poll_src(flg0, rg, w, l, (u32)t);
      gemm_half(h0s + (size_t)t * (B_ * 1024), rg, w, lr, lq, bfragA, acc);
    }

    // ---- K-split reduction through LDS (per-wave region; barrier gates reads)
#pragma unroll
    for (int mt = 0; mt < 2; ++mt)
#pragma unroll
      for (int nt = 0; nt < 4; ++nt)
#pragma unroll
        for (int rr = 0; rr < 4; ++rr)
          partial[w][mt * 16 + lq * 4 + rr][nt * 16 + lr] = acc[mt][nt][rr];
    __syncthreads();

    // ---- cell
    float g4[4];
#pragma unroll
    for (int g = 0; g < 4; ++g) {
      float ssum = xgv[g];
#pragma unroll
      for (int p = 0; p < 8; ++p) ssum += partial[p][cm][g * 16 + cu];
      g4[g] = ssum;
    }
    float cn = sigm(g4[1]) * creg + sigm(g4[0]) * tanhf(g4[2]);
    float hn = sigm(g4[3]) * tanhf(cn);
    creg = cn;
    if (EMIT && layer) hsf[(size_t)t * (B_ * H_) + m_c * H_ + unit] = hn;
    if (t == T - 1) { cL[m_c * H_ + unit] = cn; hL[m_c * H_ + unit] = hn; }
    u16 hh = bf16_rn(hn);
    u16 hl2 = bf16_rn(hn - bf16_f(hh));
    u32 packed = (u32)hh | ((u32)hl2 << 16);
    u32* hnext = hsl + (size_t)(t + 1) * (B_ * 1024);
    u32 hidx = m_c * 1024 + ((unit >> 5) << 5) +
               ((((unit >> 2) & 7) ^ (m_c & 7)) << 2) + (unit & 3);
    {
      u32* sp = hnext + hidx;
      asm volatile("global_store_dword %0, %1, off sc0 sc1"
                   :: "v"(sp), "v"(packed) : "memory");
    }

    // ---- publish (layer-0 always: layer-1 consumes even the last slot)
    if (!layer || t < T - 1) {
      asm volatile("s_waitcnt vmcnt(0)" ::: "memory");
      __syncthreads();
      if (tid == 0)
        __hip_atomic_store(flgS + (size_t)((rg << 6) + ct) * 4, (u32)(t + 1),
                           __ATOMIC_RELAXED, __HIP_MEMORY_SCOPE_AGENT);
    }
  }
}

// --------- single-step kernel (tiny-ws fallback), perm_g cell --------------
__launch_bounds__(256)
__global__ void rnn_step(const u16* __restrict__ hprev, const u16* __restrict__ Wb,
                         const float* __restrict__ xg,
                         float* __restrict__ c, float* __restrict__ hf,
                         u32* __restrict__ hout) {
  __shared__ char smem[32768];
  u16* lsA = (u16*)smem;
  u16* lsB = (u16*)(smem + 16384);
  const int nt = blockIdx.x, n0 = nt * 64;
  const int tid = threadIdx.x, w = tid >> 6, l = tid & 63;
  const int lr = l & 15, lq = l >> 4;
  f32x4 acc[4] = {};
  for (int kt = 0; kt < 16; ++kt) {
#pragma unroll
    for (int i = 0; i < 4; ++i) {
      int rb = w * 16 + i * 4;
      const u16* ga = hprev + (size_t)(rb + (l >> 4)) * 2048 + kt * 128 + (l & 15) * 8;
      __builtin_amdgcn_global_load_lds(
          (const __attribute__((address_space(1))) void*)ga,
          (__attribute__((address_space(3))) void*)(lsA + rb * 128), 16, 0, 0);
      const u16* gb = Wb + (size_t)(n0 + rb + (l >> 4)) * 2048 + kt * 128 + (l & 15) * 8;
      __builtin_amdgcn_global_load_lds(
          (const __attribute__((address_space(1))) void*)gb,
          (__attribute__((address_space(3))) void*)(lsB + rb * 128), 16, 0, 0);
    }
    asm volatile("s_waitcnt vmcnt(0)" ::: "memory");
    __syncthreads();
    bf16x8 af[4];
    int ar = w * 16 + lr;
#pragma unroll
    for (int s = 0; s < 4; ++s)
      af[s] = *(const bf16x8*)&lsA[ar * 128 + (s >> 1) * 64 + ((((s & 1) << 2) + lq) ^ (ar & 7)) * 8];
#pragma unroll
    for (int jj = 0; jj < 4; ++jj) {
      int br = jj * 16 + lr;
#pragma unroll
      for (int s = 0; s < 4; ++s) {
        bf16x8 bv = *(const bf16x8*)&lsB[br * 128 + (s >> 1) * 64 + ((((s & 1) << 2) + lq) ^ (br & 7)) * 8];
        acc[jj] = __builtin_amdgcn_mfma_f32_16x16x32_bf16(af[s], bv, acc[jj], 0, 0, 0);
      }
    }
    __syncthreads();
  }
  float* gsh = (float*)smem;
#pragma unroll
  for (int jj = 0; jj < 4; ++jj)
#pragma unroll
    for (int rr = 0; rr < 4; ++rr)
      gsh[(w * 16 + lq * 4 + rr) * 68 + jj * 16 + lr] = acc[jj][rr];
  __syncthreads();
  const int ui = tid & 15, mq = tid >> 4;
#pragma unroll
  for (int mr = 0; mr < 4; ++mr) {
    int m = mr * 16 + mq;
    float gi = gsh[m * 68 + 0 + ui]  + xg[(size_t)m * G_ + n0 + 0 + ui];
    float gf = gsh[m * 68 + 16 + ui] + xg[(size_t)m * G_ + n0 + 16 + ui];
    float gg = gsh[m * 68 + 32 + ui] + xg[(size_t)m * G_ + n0 + 32 + ui];
    float go = gsh[m * 68 + 48 + ui] + xg[(size_t)m * G_ + n0 + 48 + ui];
    int unit = nt * 16 + ui;
    int ci = m * H_ + unit;
    float cn = sigm(gf) * c[ci] + sigm(gi) * tanhf(gg);
    float hn = sigm(go) * tanhf(cn);
    c[ci] = cn;
    hf[ci] = hn;
    u16 hh = bf16_rn(hn);
    u16 hl = bf16_rn(hn - bf16_f(hh));
    u32 hidx = m * 1024 + ((unit >> 5) << 5) +
               ((((unit >> 2) & 7) ^ (m & 7)) << 2) + (unit & 3);
    hout[hidx] = (u32)hh | ((u32)hl << 16);
  }
}

// ---------------------------------------------------------------------------
extern "C" void kernel_launch(void* const* d_in, const int* in_sizes, int n_in,
                              void* d_out, int out_size, void* d_ws, size_t ws_size,
                              hipStream_t stream) {
  const int*   word  = (const int*)  d_in[0];
  const int*   seq   = (const int*)  d_in[1];
  const float* emb   = (const float*)d_in[2];
  const float* w2h_W = (const float*)d_in[3];
  const float* w2h_b = (const float*)d_in[4];
  const float* W_ih0 = (const float*)d_in[5];
  const float* W_hh0 = (const float*)d_in[6];
  const float* b_ih0 = (const float*)d_in[7];
  const float* b_hh0 = (const float*)d_in[8];
  const float* W_ih1 = (const float*)d_in[9];
  const float* W_hh1 = (const float*)d_in[10];
  const float* b_ih1 = (const float*)d_in[11];
  const float* b_hh1 = (const float*)d_in[12];
  const float* dec_W = (const float*)d_in[13];
  const float* dec_b = (const float*)d_in[14];

  float* out = (float*)d_out;
  float* hL0 = out + 102400000;
  float* hL1 = hL0 + B_ * H_;
  float* cL0 = out + 102531072;
  float* cL1 = cL0 + B_ * H_;

  // scratch in d_out (clobber-safe: decoder writes [0,102.4M) last)
  float* xg0      = out;                       // [3200,4096]
  u16*   x0w_bf   = (u16*)(out + 13200000);    // [64,2048]
  u16*   x0seq_bf = (u16*)(out + 13300000);    // [3200,2048]
  u32*   hs0slots = (u32*)(out + 16600000);    // [51][64][1024] u32-packed
  u16*   wih0a_bf = (u16*)(out + 20000000);    // [4096,2048] each
  u16*   wih0b_bf = (u16*)(out + 24200000);
  u16*   wih1_bf  = (u16*)(out + 28400000);
  u16*   whh0_bf  = (u16*)(out + 32600000);
  u16*   whh1_bf  = (u16*)(out + 36800000);
  float* y_w      = out + 73800000;            // [64,4096]
  float* bias0p   = out + 74400000;
  float* bias1p   = out + 74410000;
  float* xg1      = out + 87560192;            // tier3 only
  u32*   h1alt    = (u32*)(out + 91000000);    // tier2 h1 slots [51][64][1024]
  u32*   flg0     = (u32*)(out + 101000000);   // 128 flags x 4 u32 (16B stride)
  u32*   hbfA     = (u32*)(out + 101100000);   // tier3 ping-pong
  u32*   hbfB     = (u32*)(out + 101200000);

  const size_t need_hs1  = (size_t)T_ * B_ * H_ * 4;
  const size_t need_full = (size_t)V_ * 2048 * 2 + (size_t)(T_ + 1) * B_ * 1024 * 4;
  const bool tier1 = ws_size >= need_full;
  const bool tier2 = !tier1 && ws_size >= need_hs1;

  u16*   decW_bf  = (u16*)d_ws;
  u32*   hs1slots = (u32*)d_ws + (size_t)V_ * 1024;
  float* hs1f     = (float*)d_ws;

  // ONE init launch: flags (both sets), h0 slot0, h1 slot0, permuted biases
  init_all<<<576, 256, 0, stream>>>(
      out + 101000000, (float*)hs0slots,
      tier1 ? (float*)hs1slots : (tier2 ? (float*)h1alt : nullptr),
      b_ih0, b_hh0, bias0p, b_ih1, b_hh1, bias1p);

  // c0 = word_emb @ w2h_W^T + w2h_b  (identical for both layers: dual store)
  gemm_nt<64, 64, 16, 4, 4><<<dim3(16, 1), 256, 0, stream>>>(
      emb, word, E_, w2h_W, E_, 0, w2h_b, cL0, cL1, H_, B_, H_, E_);

  // ONE conversion launch for all weights + gathered embeddings
  conv_all<<<11872, 256, 0, stream>>>(
      W_ih0, W_ih1, W_hh0, W_hh1, emb, word, seq,
      wih0a_bf, wih0b_bf, wih1_bf, whh0_bf, whh1_bf, x0w_bf, x0seq_bf);

  // dec_W conversion: serial (r18 proved co-residency with rnn costs 3x)
  if (tier1)
    conv_w<<<16000, 256, 0, stream>>>(dec_W, H_, 0, nullptr, 0, V_, decW_bf);

  // y_w, xg0
  gemm_bt<<<32, 256, 0, stream>>>(x0w_bf, B_, wih0a_bf, bias0p,
                                  nullptr, 0, -1, y_w, G_, G_, 32, 1, 0);
  gemm_bt<<<800, 256, 0, stream>>>(x0seq_bf, T_ * B_, wih0b_bf, nullptr,
                                   y_w, G_, 63, xg0, G_, G_, 32, 25, 0);

  if (tier1) {
    rnn_dual<true, false><<<256, 512, 0, stream>>>(
        whh0_bf, whh1_bf, wih1_bf, xg0, bias1p,
        cL0, hL0, cL1, hL1, hs0slots, hs1slots, nullptr, flg0, flg0 + 1024, T_);
    gemm_bt<<<6250, 256, 0, stream>>>((const u16*)(hs1slots + (size_t)B_ * 1024),
                                      T_ * B_, decW_bf, dec_b,
                                      nullptr, 0, -1, out, V_, V_, 250, 25, 1);
  } else if (tier2) {
    rnn_dual<true, true><<<256, 512, 0, stream>>>(
        whh0_bf, whh1_bf, wih1_bf, xg0, bias1p,
        cL0, hL0, cL1, hL1, hs0slots, h1alt, hs1f, flg0, flg0 + 1024, T_);
    gemm_sp<<<6250, 256, 0, stream>>>(
        hs1f, H_, dec_W, H_, dec_b, out, V_, T_ * B_, V_, H_, 250);
  } else {
    // tier3: layer-0 solo persistent, then sequential layer-1 + decode
    rnn_dual<false, false><<<128, 512, 0, stream>>>(
        whh0_bf, whh1_bf, wih1_bf, xg0, bias1p,
        cL0, hL0, cL1, hL1, hs0slots, nullptr, nullptr, flg0, flg0 + 1024, T_);
    gemm_bt<<<800, 256, 0, stream>>>((const u16*)(hs0slots + (size_t)B_ * 1024),
                                     T_ * B_, wih1_bf, bias1p,
                                     nullptr, 0, -1, xg1, G_, G_, 32, 25, 0);
    for (int t = 0; t < T_; ++t) {
      const u16* hp = t ? (const u16*)((t & 1) ? hbfA : hbfB) : (const u16*)hs0slots;
      u32* ho = (t & 1) ? hbfB : hbfA;
      rnn_step<<<64, 256, 0, stream>>>(
          hp, whh1_bf, xg1 + (size_t)t * B_ * G_, cL1, hL1, ho);
      gemm_sp<<<250, 256, 0, stream>>>(
          hL1, H_, dec_W, H_, dec_b, out + (size_t)t * B_ * V_, V_, B_, V_, H_, 250);
    }
  }
}